// Round 11
// baseline (634.227 us; speedup 1.0000x reference)
//
#include <hip/hip_runtime.h>
#include <math.h>

// CapsuleLayer dynamic routing — round 18: depth-4 register pipeline.
// B=64, N=4096, I=8, C=32, D=16, 3 routing iterations.
//
// Round-17 post-mortem: halving load count was NULL (-0.7us); r14 halving
// barriers was ~null too. pass12 streams ~72MB at only ~2.2 TB/s (3x below
// achievable) with every pipe <12% busy -> per-wave MLP bound: prefetch is
// 1 iteration deep (3KB/wave in flight) and the per-iter barrier gates load
// issue. Round 18 (one mechanism, both pass kernels): quad-buffered register
// pipeline, loads issued 4 iterations ahead, loops FULLY unrolled so all
// buffer indices are compile-time constants (runtime-indexed vectors spill).
// In-flight/wave: 3KB -> 12KB. No layout/math/dispatch changes (r17 base).
//
// ws (NPB=16): Wh fp16 32 MiB | partial u32(h2) 16 MiB | xh fp16 4 MiB |
//              OcumG fp16 64 KiB (52.07)

typedef __fp16 h2 __attribute__((ext_vector_type(2)));
typedef __fp16 half4 __attribute__((ext_vector_type(4)));
typedef float f32x16 __attribute__((ext_vector_type(16)));

union U2 { h2 h; unsigned u; };

__device__ __forceinline__ float fdot2(h2 a, h2 b, float c) {
    return __builtin_amdgcn_fdot2(a, b, c, false);
}
__device__ __forceinline__ h2 uash2(unsigned u) { U2 t; t.u = u; return t.h; }

// ---- pass 0: uniform coupling; cj-split; LDS-staged x; emits Wh and xh ----

template <int NPB>
__global__ __launch_bounds__(512, 4) void pass0_kernel(
    const float* __restrict__ W,      // [C][N][D][I] f32
    const float* __restrict__ x,      // [B][N][I] f32
    ushort* __restrict__ Wh,          // [np][cj][hi][par][i4] fp16
    ushort* __restrict__ xh,          // [np][b][hi][par][i4] fp16
    unsigned* __restrict__ partial)   // [(bt*NB+nblk)][bl 32][cjp 256] u32(h2)
{
    constexpr int NB = 4096 / NPB;
    const int bid = blockIdx.x;
    const int half = bid / NB, nblk = bid % NB;      // XCD = bid%8 = nblk%8
    const int n0 = nblk * NPB;
    const int t = threadIdx.x, l = t & 63, w = t >> 6;
    const int bl = l & 31, hi = l >> 5;
    const int cj = half * 256 + w * 32 + bl;         // this lane's A-row

    __shared__ __align__(16) ushort xs[NPB * 512];   // [n][b][i] fp16, swizzled
    __shared__ unsigned sep[8192];                   // 32KB epilogue staging

    // ---- stage x tile: coalesced f32 read -> fp16 -> swizzled LDS --------
    #pragma unroll
    for (int rep = 0; rep < NPB / 4; ++rep) {
        const int idx = t + rep * 512;               // float4 id, 0..NPB*128-1
        const int b = idx / (2 * NPB), f4 = idx % (2 * NPB);
        const int nl = f4 >> 1, isl = f4 & 1;
        float4 v = *reinterpret_cast<const float4*>(
            x + (size_t)b * 32768 + (size_t)n0 * 8 + f4 * 4);
        half4 h;
        h[0] = (__fp16)v.x; h[1] = (__fp16)v.y; h[2] = (__fp16)v.z; h[3] = (__fp16)v.w;
        const int slot = (nl * 128 + b * 2 + isl) ^ ((nl & 7) << 1) ^ ((b >> 3) & 3);
        *reinterpret_cast<half4*>(xs + slot * 4) = h;
    }
    __syncthreads();

    // ---- emit xh (paired layout) from LDS (half==0 blocks only) ----------
    if (half == 0) {
        #pragma unroll
        for (int rep = 0; rep < NPB / 4; ++rep) {
            const int u = t + rep * 512;             // half4 id = (nl, b, isl)
            const int nl = u >> 7, b = (u >> 1) & 63, isl = u & 1;
            const int slot = (nl * 128 + b * 2 + isl) ^ ((nl & 7) << 1) ^ ((b >> 3) & 3);
            half4 h = *reinterpret_cast<const half4*>(xs + slot * 4);
            // xh[np][b][isl(=hi)][par][i4]
            const size_t dst = (((size_t)((n0 >> 1) + (nl >> 1)) * 64 + b) * 2 + isl) * 8
                               + (nl & 1) * 4;
            *reinterpret_cast<half4*>(xh + dst) = h;
        }
    }

    const float* wb = W + (size_t)(cj >> 4) * 524288 + (size_t)n0 * 128 + (cj & 15) * 8 + hi * 4;
    ushort* whp = Wh + ((size_t)(n0 >> 1) * 512 + cj) * 16 + hi * 8;  // paired

    f32x16 acc0 = {}, acc1 = {};                     // b 0-31 / b 32-63

    // depth-4 register pipeline on the W stream (fully unrolled loop ->
    // all wr[] indices compile-time constant)
    float4 wr[4];
    #pragma unroll
    for (int i = 0; i < 4; ++i)
        wr[i] = *reinterpret_cast<const float4*>(wb + i * 128);

    #pragma unroll
    for (int s = 0; s < NPB; ++s) {
        const float4 wv = wr[s & 3];
        if (s + 4 < NPB)
            wr[s & 3] = *reinterpret_cast<const float4*>(wb + (s + 4) * 128);
        const int sw = ((s & 7) << 1) ^ ((bl >> 3) & 3);
        const int slot0 = (s * 128 + bl * 2 + hi) ^ sw;
        const int slot1 = (s * 128 + bl * 2 + 64 + hi) ^ sw;
        half4 b0 = *reinterpret_cast<const half4*>(xs + slot0 * 4);
        half4 b1 = *reinterpret_cast<const half4*>(xs + slot1 * 4);
        half4 a;
        a[0] = (__fp16)wv.x; a[1] = (__fp16)wv.y; a[2] = (__fp16)wv.z; a[3] = (__fp16)wv.w;
        *reinterpret_cast<half4*>(whp + (size_t)(s >> 1) * 8192 + (s & 1) * 4) = a;
        acc0 = __builtin_amdgcn_mfma_f32_32x32x8f16(a, b0, acc0, 0, 0, 0);
        acc1 = __builtin_amdgcn_mfma_f32_32x32x8f16(a, b1, acc1, 0, 0, 0);
    }
    #pragma unroll
    for (int r = 0; r < 16; ++r) { acc0[r] *= 0.03125f; acc1[r] *= 0.03125f; }

    // epilogue: sep[b 64][cjp_local 128], XOR-swizzled by b
    #pragma unroll
    for (int hb = 0; hb < 2; ++hb) {
        #pragma unroll
        for (int q = 0; q < 8; ++q) {
            const float e0 = hb ? acc1[2 * q] : acc0[2 * q];
            const float e1 = hb ? acc1[2 * q + 1] : acc0[2 * q + 1];
            U2 u; u.h = __builtin_amdgcn_cvt_pkrtz(e0, e1);
            const int cjp = w * 16 + 4 * (q >> 1) + (q & 1) + 2 * hi;  // local
            const int bb = bl + 32 * hb;
            sep[bb * 128 + (cjp ^ bb)] = u.u;
        }
    }
    __syncthreads();
    #pragma unroll
    for (int u2 = 0; u2 < 16; ++u2) {
        const int idx = t + u2 * 512;                // 0..8191
        const int ub = idx >> 7, ucjp = idx & 127;
        partial[(size_t)((ub >> 5) * NB + nblk) * 8192 + (ub & 31) * 256 + half * 128 + ucjp]
            = sep[ub * 128 + (ucjp ^ ub)];
    }
}

// ---- pass 1/2: softmax coupling; 2 n-steps per barrier; fp16 acc ----------

template <int NPB>
__global__ __launch_bounds__(512, 4) void pass12_kernel(
    const ushort* __restrict__ Wh,    // [np][cj][hi][par][i4] fp16
    const ushort* __restrict__ xh,    // [np][b][hi][par][i4] fp16
    const ushort* __restrict__ OcumG, // [B][CJ] fp16
    unsigned* __restrict__ partial)   // [bid][bl 32][cjp 256] u32(h2)
{
    constexpr int NB = 4096 / NPB;
    const int bid = blockIdx.x;
    const int bt = bid / NB, nblk = bid % NB;
    const int n0 = nblk * NPB;
    const int t = threadIdx.x, l = t & 63, w = t >> 6;
    const int bl = l & 31, hi = l >> 5;
    const int b = bt * 32 + bl;

    __shared__ __align__(16) float pd[2][2][32][12]; // [buf][sub][b][wave]
    __shared__ unsigned sep[8192];                   // 32KB epilogue staging

    const int cj0 = w * 64 + bl, cj1 = cj0 + 32;
    const ushort* xb = xh + (((size_t)(n0 >> 1) * 64 + b) * 2 + hi) * 8;
    const ushort* whp0 = Wh + ((size_t)(n0 >> 1) * 512 + cj0) * 16 + hi * 8;
    const ushort* whp1 = Wh + ((size_t)(n0 >> 1) * 512 + cj1) * 16 + hi * 8;

    h2 oc[2][8];
    {
        const unsigned* og = reinterpret_cast<const unsigned*>(OcumG);
        #pragma unroll
        for (int mt = 0; mt < 2; ++mt) {
            const int cA = 4 * w + 2 * mt;
            const unsigned idx = (unsigned)b * 256 + cA * 8 + hi * 2;
            oc[mt][0] = uash2(og[idx]);      oc[mt][1] = uash2(og[idx + 1]);
            oc[mt][2] = uash2(og[idx + 4]);  oc[mt][3] = uash2(og[idx + 5]);
            oc[mt][4] = uash2(og[idx + 8]);  oc[mt][5] = uash2(og[idx + 9]);
            oc[mt][6] = uash2(og[idx + 12]); oc[mt][7] = uash2(og[idx + 13]);
        }
    }

    f32x16 zero = {};
    h2 acc0h[8], acc1h[8];                           // fp16 accumulators
    #pragma unroll
    for (int q = 0; q < 8; ++q) {
        acc0h[q] = (h2)(__fp16)0.f;
        acc1h[q] = (h2)(__fp16)0.f;
    }

    // depth-4 register pipeline (fully unrolled loop -> static indices)
    uint4 w0r[4], w1r[4], xvr[4];
    #pragma unroll
    for (int i = 0; i < 4; ++i) {
        w0r[i] = *reinterpret_cast<const uint4*>(whp0 + (size_t)i * 8192);
        w1r[i] = *reinterpret_cast<const uint4*>(whp1 + (size_t)i * 8192);
        xvr[i] = *reinterpret_cast<const uint4*>(xb + (size_t)i * 1024);
    }

    #pragma unroll
    for (int p = 0; p < NPB / 2; ++p) {
        const uint4 w0 = w0r[p & 3];
        const uint4 w1 = w1r[p & 3];
        const uint4 xv = xvr[p & 3];
        if (p + 4 < NPB / 2) {
            w0r[p & 3] = *reinterpret_cast<const uint4*>(whp0 + (size_t)(p + 4) * 8192);
            w1r[p & 3] = *reinterpret_cast<const uint4*>(whp1 + (size_t)(p + 4) * 8192);
            xvr[p & 3] = *reinterpret_cast<const uint4*>(xb + (size_t)(p + 4) * 1024);
        }
        const half4* w0h = reinterpret_cast<const half4*>(&w0);
        const half4* w1h = reinterpret_cast<const half4*>(&w1);
        const half4* xvh = reinterpret_cast<const half4*>(&xv);
        const half4 a0A = w0h[0], a0B = w0h[1];
        const half4 a1A = w1h[0], a1B = w1h[1];
        const half4 bfA = xvh[0], bfB = xvh[1];

        // ---- sub-step A -----------------------------------------------
        h2 hA0[8], hA1[8];
        {
            f32x16 d0 = __builtin_amdgcn_mfma_f32_32x32x8f16(a0A, bfA, zero, 0, 0, 0);
            f32x16 d1 = __builtin_amdgcn_mfma_f32_32x32x8f16(a1A, bfA, zero, 0, 0, 0);
            #pragma unroll
            for (int q = 0; q < 8; ++q) {
                hA0[q] = __builtin_amdgcn_cvt_pkrtz(d0[2 * q], d0[2 * q + 1]);
                hA1[q] = __builtin_amdgcn_cvt_pkrtz(d1[2 * q], d1[2 * q + 1]);
            }
        }
        float pA0_A = fdot2(hA0[3], oc[0][3], fdot2(hA0[2], oc[0][2], fdot2(hA0[1], oc[0][1], fdot2(hA0[0], oc[0][0], 0.f))));
        float pB0_A = fdot2(hA0[7], oc[0][7], fdot2(hA0[6], oc[0][6], fdot2(hA0[5], oc[0][5], fdot2(hA0[4], oc[0][4], 0.f))));
        float pA1_A = fdot2(hA1[3], oc[1][3], fdot2(hA1[2], oc[1][2], fdot2(hA1[1], oc[1][1], fdot2(hA1[0], oc[1][0], 0.f))));
        float pB1_A = fdot2(hA1[7], oc[1][7], fdot2(hA1[6], oc[1][6], fdot2(hA1[5], oc[1][5], fdot2(hA1[4], oc[1][4], 0.f))));
        // ---- sub-step B -----------------------------------------------
        h2 hB0[8], hB1[8];
        {
            f32x16 d0 = __builtin_amdgcn_mfma_f32_32x32x8f16(a0B, bfB, zero, 0, 0, 0);
            f32x16 d1 = __builtin_amdgcn_mfma_f32_32x32x8f16(a1B, bfB, zero, 0, 0, 0);
            #pragma unroll
            for (int q = 0; q < 8; ++q) {
                hB0[q] = __builtin_amdgcn_cvt_pkrtz(d0[2 * q], d0[2 * q + 1]);
                hB1[q] = __builtin_amdgcn_cvt_pkrtz(d1[2 * q], d1[2 * q + 1]);
            }
        }
        float pA0_B = fdot2(hB0[3], oc[0][3], fdot2(hB0[2], oc[0][2], fdot2(hB0[1], oc[0][1], fdot2(hB0[0], oc[0][0], 0.f))));
        float pB0_B = fdot2(hB0[7], oc[0][7], fdot2(hB0[6], oc[0][6], fdot2(hB0[5], oc[0][5], fdot2(hB0[4], oc[0][4], 0.f))));
        float pA1_B = fdot2(hB1[3], oc[1][3], fdot2(hB1[2], oc[1][2], fdot2(hB1[1], oc[1][1], fdot2(hB1[0], oc[1][0], 0.f))));
        float pB1_B = fdot2(hB1[7], oc[1][7], fdot2(hB1[6], oc[1][6], fdot2(hB1[5], oc[1][5], fdot2(hB1[4], oc[1][4], 0.f))));

        pA0_A += __shfl_xor(pA0_A, 32, 64);
        pB0_A += __shfl_xor(pB0_A, 32, 64);
        pA1_A += __shfl_xor(pA1_A, 32, 64);
        pB1_A += __shfl_xor(pB1_A, 32, 64);
        pA0_B += __shfl_xor(pA0_B, 32, 64);
        pB0_B += __shfl_xor(pB0_B, 32, 64);
        pA1_B += __shfl_xor(pA1_B, 32, 64);
        pB1_B += __shfl_xor(pB1_B, 32, 64);

        float eA0_A = __expf(pA0_A), eB0_A = __expf(pB0_A);
        float eA1_A = __expf(pA1_A), eB1_A = __expf(pB1_A);
        float eA0_B = __expf(pA0_B), eB0_B = __expf(pB0_B);
        float eA1_B = __expf(pA1_B), eB1_B = __expf(pB1_B);

        const int buf = p & 1;
        if (l < 32) {
            pd[buf][0][bl][w] = eA0_A + eB0_A + eA1_A + eB1_A;
            pd[buf][1][bl][w] = eA0_B + eB0_B + eA1_B + eB1_B;
        }
        __syncthreads();
        const float4 qa0 = *reinterpret_cast<const float4*>(&pd[buf][0][bl][0]);
        const float4 qa1 = *reinterpret_cast<const float4*>(&pd[buf][0][bl][4]);
        const float4 qb0 = *reinterpret_cast<const float4*>(&pd[buf][1][bl][0]);
        const float4 qb1 = *reinterpret_cast<const float4*>(&pd[buf][1][bl][4]);
        const float rdA = __builtin_amdgcn_rcpf(qa0.x + qa0.y + qa0.z + qa0.w +
                                                qa1.x + qa1.y + qa1.z + qa1.w);
        const float rdB = __builtin_amdgcn_rcpf(qb0.x + qb0.y + qb0.z + qb0.w +
                                                qb1.x + qb1.y + qb1.z + qb1.w);

        h2 c0A, c1A, c0B, c1B, c2A, c3A, c2B, c3B;
        c0A.x = (__fp16)(eA0_A * rdA); c0A.y = c0A.x;  // acc0 rows<8  (c=4w)
        c1A.x = (__fp16)(eB0_A * rdA); c1A.y = c1A.x;  // acc0 rows>=8 (c=4w+1)
        c2A.x = (__fp16)(eA1_A * rdA); c2A.y = c2A.x;  // acc1 rows<8  (c=4w+2)
        c3A.x = (__fp16)(eB1_A * rdA); c3A.y = c3A.x;  // acc1 rows>=8 (c=4w+3)
        c0B.x = (__fp16)(eA0_B * rdB); c0B.y = c0B.x;
        c1B.x = (__fp16)(eB0_B * rdB); c1B.y = c1B.x;
        c2B.x = (__fp16)(eA1_B * rdB); c2B.y = c2B.x;
        c3B.x = (__fp16)(eB1_B * rdB); c3B.y = c3B.x;

        #pragma unroll
        for (int q = 0; q < 4; ++q) {
            acc0h[q] = hA0[q] * c0A + acc0h[q];
            acc0h[q + 4] = hA0[q + 4] * c1A + acc0h[q + 4];
            acc1h[q] = hA1[q] * c2A + acc1h[q];
            acc1h[q + 4] = hA1[q + 4] * c3A + acc1h[q + 4];
        }
        #pragma unroll
        for (int q = 0; q < 4; ++q) {
            acc0h[q] = hB0[q] * c0B + acc0h[q];
            acc0h[q + 4] = hB0[q + 4] * c1B + acc0h[q + 4];
            acc1h[q] = hB1[q] * c2B + acc1h[q];
            acc1h[q + 4] = hB1[q + 4] * c3B + acc1h[q + 4];
        }
    }

    // ---- epilogue: stage h2 partial tile in LDS (XOR-swizzled), copy out --
    __syncthreads();
    #pragma unroll
    for (int mt = 0; mt < 2; ++mt) {
        #pragma unroll
        for (int q = 0; q < 8; ++q) {
            U2 u; u.h = mt ? acc1h[q] : acc0h[q];
            const int cjp = w * 32 + mt * 16 + 4 * (q >> 1) + (q & 1) + 2 * hi;
            sep[bl * 256 + (cjp ^ bl)] = u.u;   // swizzle: conflict-free banks
        }
    }
    __syncthreads();
    const unsigned gbase = (unsigned)bid * 8192;
    #pragma unroll
    for (int u2 = 0; u2 < 16; ++u2) {
        const int idx = t + u2 * 512;
        const int ubl = idx >> 8, ucjp = idx & 255;
        partial[gbase + idx] = sep[ubl * 256 + (ucjp ^ ubl)];
    }
}

// ---- final reduce + squash + Ocum update (4 threads per output) -----------

template <int NB>
__global__ __launch_bounds__(256) void reduce_squash(const unsigned* __restrict__ partial32,
                                                     ushort* __restrict__ OcumG,
                                                     float* __restrict__ out,
                                                     int passIdx) {
    const int gtid = blockIdx.x * 256 + threadIdx.x;  // 0..65535
    const int oid = gtid >> 2, sub = gtid & 3;
    const int b = oid >> 8, cjp = oid & 255;
    const int bt = b >> 5, bl = b & 31;
    const unsigned base = (unsigned)bt * (unsigned)NB * 8192u + (unsigned)bl * 256u + (unsigned)cjp;
    float sx = 0.f, sy = 0.f;
    #pragma unroll 8
    for (int i = 0; i < NB / 4; ++i) {
        U2 v; v.u = partial32[base + (unsigned)(sub + 4 * i) * 8192u];
        sx += (float)v.h.x;
        sy += (float)v.h.y;
    }
    sx += __shfl_xor(sx, 1, 64); sy += __shfl_xor(sy, 1, 64);
    sx += __shfl_xor(sx, 2, 64); sy += __shfl_xor(sy, 2, 64);
    float s2 = sx * sx + sy * sy;                    // sum over capsule's 8 cjp
    s2 += __shfl_xor(s2, 4, 64);
    s2 += __shfl_xor(s2, 8, 64);
    s2 += __shfl_xor(s2, 16, 64);
    float scale = (s2 / (1.f + s2)) / sqrtf(s2 + 1e-7f);
    float o0 = scale * sx, o1 = scale * sy;

    if (sub == 0) {
        unsigned* ocp = reinterpret_cast<unsigned*>(OcumG) + b * 256 + cjp;
        float a0 = o0, a1 = o1;
        if (passIdx) {
            U2 old; old.u = *ocp;
            a0 += (float)old.h.x;
            a1 += (float)old.h.y;
        }
        U2 nw; nw.h = __builtin_amdgcn_cvt_pkrtz(a0, a1);
        *ocp = nw.u;
        if (passIdx == 2) {
            out[b * 512 + cjp * 2] = o0;
            out[b * 512 + cjp * 2 + 1] = o1;
        }
    }
}

// ---- host ------------------------------------------------------------------

extern "C" void kernel_launch(void* const* d_in, const int* in_sizes, int n_in,
                              void* d_out, int out_size, void* d_ws, size_t ws_size,
                              hipStream_t stream) {
    const float* x = (const float*)d_in[0];
    const float* W = (const float*)d_in[1];
    float* out = (float*)d_out;

    char* ws = (char*)d_ws;
    ushort* Wh = (ushort*)ws;                                        // 32 MiB
    const size_t MiB = 1024 * 1024;

    if (ws_size >= 52 * MiB + 65536) {
        // NPB=16: partial 16 MiB | xh 4 MiB | Ocum 64 KiB
        unsigned* partialU = (unsigned*)(ws + 32 * MiB);
        ushort* xh = (ushort*)(ws + 48 * MiB);
        ushort* OcumG = (ushort*)(ws + 52 * MiB);
        pass0_kernel<16><<<512, 512, 0, stream>>>(W, x, Wh, xh, partialU);
        reduce_squash<256><<<256, 256, 0, stream>>>(partialU, OcumG, out, 0);
        pass12_kernel<16><<<512, 512, 0, stream>>>(Wh, xh, OcumG, partialU);
        reduce_squash<256><<<256, 256, 0, stream>>>(partialU, OcumG, out, 1);
        pass12_kernel<16><<<512, 512, 0, stream>>>(Wh, xh, OcumG, partialU);
        reduce_squash<256><<<256, 256, 0, stream>>>(partialU, OcumG, out, 2);
    } else {
        // fallback NPB=32: partial 8 MiB | xh 4 MiB | Ocum 64 KiB (44.07 MiB)
        unsigned* partialU = (unsigned*)(ws + 32 * MiB);
        ushort* xh = (ushort*)(ws + 40 * MiB);
        ushort* OcumG = (ushort*)(ws + 44 * MiB);
        pass0_kernel<32><<<256, 512, 0, stream>>>(W, x, Wh, xh, partialU);
        reduce_squash<128><<<256, 256, 0, stream>>>(partialU, OcumG, out, 0);
        pass12_kernel<32><<<256, 512, 0, stream>>>(Wh, xh, OcumG, partialU);
        reduce_squash<128><<<256, 256, 0, stream>>>(partialU, OcumG, out, 1);
        pass12_kernel<32><<<256, 512, 0, stream>>>(Wh, xh, OcumG, partialU);
        reduce_squash<128><<<256, 256, 0, stream>>>(partialU, OcumG, out, 2);
    }
}

// Round 12
// 169.879 us; speedup vs baseline: 3.7334x; 3.7334x over previous
//
#include <hip/hip_runtime.h>
#include <math.h>

// CapsuleLayer dynamic routing — round 19: global_load_lds Wh staging.
// B=64, N=4096, I=8, C=32, D=16, 3 routing iterations.
//
// Round-18 post-mortem: depth-4 reg pipeline SPILLED (WRITE 390MB scratch,
// 265us) — and r16's "thrash" (WRITE 266MB) was the same spill pathology.
// Lesson: deepening the pipeline in VGPRs spills; the clean r17 kernel is
// latency-bound on the Wh VGPR load path (1-iter prefetch).
// Round 19 (r17 base + one mechanism): move Wh off the VGPR path with
// async global_load_lds, double-buffered per n-pair slice (16KB = 512 cj
// records). Per iter each wave issues 2x 16B global_load_lds; the existing
// per-iteration __syncthreads (implicit vmcnt drain) guarantees arrival one
// iteration later; buffer reuse is ordered by the same barrier. LDS layout
// [hi][cj] -> reader lanes at 64B stride = minimal bank aliasing. Register
// pressure DROPS (~64->~50). x/Ocum regs, pass0, reduce, all math = r17.
//
// ws (NPB=16): Wh fp16 32 MiB | partial u32(h2) 16 MiB | xh fp16 4 MiB |
//              OcumG fp16 64 KiB (52.07)

typedef __fp16 h2 __attribute__((ext_vector_type(2)));
typedef __fp16 half4 __attribute__((ext_vector_type(4)));
typedef float f32x16 __attribute__((ext_vector_type(16)));

union U2 { h2 h; unsigned u; };

typedef __attribute__((address_space(3))) ushort lds_us;
typedef __attribute__((address_space(1))) const ushort glb_us;

__device__ __forceinline__ float fdot2(h2 a, h2 b, float c) {
    return __builtin_amdgcn_fdot2(a, b, c, false);
}
__device__ __forceinline__ h2 uash2(unsigned u) { U2 t; t.u = u; return t.h; }

// ---- pass 0: uniform coupling; cj-split; LDS-staged x; emits Wh and xh ----

template <int NPB>
__global__ __launch_bounds__(512, 4) void pass0_kernel(
    const float* __restrict__ W,      // [C][N][D][I] f32
    const float* __restrict__ x,      // [B][N][I] f32
    ushort* __restrict__ Wh,          // [np][cj][hi][par][i4] fp16
    ushort* __restrict__ xh,          // [np][b][hi][par][i4] fp16
    unsigned* __restrict__ partial)   // [(bt*NB+nblk)][bl 32][cjp 256] u32(h2)
{
    constexpr int NB = 4096 / NPB;
    const int bid = blockIdx.x;
    const int half = bid / NB, nblk = bid % NB;      // XCD = bid%8 = nblk%8
    const int n0 = nblk * NPB;
    const int t = threadIdx.x, l = t & 63, w = t >> 6;
    const int bl = l & 31, hi = l >> 5;
    const int cj = half * 256 + w * 32 + bl;         // this lane's A-row

    __shared__ __align__(16) ushort xs[NPB * 512];   // [n][b][i] fp16, swizzled
    __shared__ unsigned sep[8192];                   // 32KB epilogue staging

    // ---- stage x tile: coalesced f32 read -> fp16 -> swizzled LDS --------
    #pragma unroll
    for (int rep = 0; rep < NPB / 4; ++rep) {
        const int idx = t + rep * 512;               // float4 id, 0..NPB*128-1
        const int b = idx / (2 * NPB), f4 = idx % (2 * NPB);
        const int nl = f4 >> 1, isl = f4 & 1;
        float4 v = *reinterpret_cast<const float4*>(
            x + (size_t)b * 32768 + (size_t)n0 * 8 + f4 * 4);
        half4 h;
        h[0] = (__fp16)v.x; h[1] = (__fp16)v.y; h[2] = (__fp16)v.z; h[3] = (__fp16)v.w;
        const int slot = (nl * 128 + b * 2 + isl) ^ ((nl & 7) << 1) ^ ((b >> 3) & 3);
        *reinterpret_cast<half4*>(xs + slot * 4) = h;
    }
    __syncthreads();

    // ---- emit xh (paired layout) from LDS (half==0 blocks only) ----------
    if (half == 0) {
        #pragma unroll
        for (int rep = 0; rep < NPB / 4; ++rep) {
            const int u = t + rep * 512;             // half4 id = (nl, b, isl)
            const int nl = u >> 7, b = (u >> 1) & 63, isl = u & 1;
            const int slot = (nl * 128 + b * 2 + isl) ^ ((nl & 7) << 1) ^ ((b >> 3) & 3);
            half4 h = *reinterpret_cast<const half4*>(xs + slot * 4);
            // xh[np][b][isl(=hi)][par][i4]
            const size_t dst = (((size_t)((n0 >> 1) + (nl >> 1)) * 64 + b) * 2 + isl) * 8
                               + (nl & 1) * 4;
            *reinterpret_cast<half4*>(xh + dst) = h;
        }
    }

    const float* wb = W + (size_t)(cj >> 4) * 524288 + (size_t)n0 * 128 + (cj & 15) * 8 + hi * 4;
    ushort* whp = Wh + ((size_t)(n0 >> 1) * 512 + cj) * 16 + hi * 8;  // paired

    f32x16 acc0 = {}, acc1 = {};                     // b 0-31 / b 32-63
    float4 wv = *reinterpret_cast<const float4*>(wb);
    #pragma unroll 1
    for (int s = 0; s < NPB; ++s) {
        float4 wvn;
        if (s < NPB - 1)
            wvn = *reinterpret_cast<const float4*>(wb + (s + 1) * 128);
        const int sw = ((s & 7) << 1) ^ ((bl >> 3) & 3);
        const int slot0 = (s * 128 + bl * 2 + hi) ^ sw;
        const int slot1 = (s * 128 + bl * 2 + 64 + hi) ^ sw;
        half4 b0 = *reinterpret_cast<const half4*>(xs + slot0 * 4);
        half4 b1 = *reinterpret_cast<const half4*>(xs + slot1 * 4);
        half4 a;
        a[0] = (__fp16)wv.x; a[1] = (__fp16)wv.y; a[2] = (__fp16)wv.z; a[3] = (__fp16)wv.w;
        *reinterpret_cast<half4*>(whp + (size_t)(s >> 1) * 8192 + (s & 1) * 4) = a;
        acc0 = __builtin_amdgcn_mfma_f32_32x32x8f16(a, b0, acc0, 0, 0, 0);
        acc1 = __builtin_amdgcn_mfma_f32_32x32x8f16(a, b1, acc1, 0, 0, 0);
        wv = wvn;
    }
    #pragma unroll
    for (int r = 0; r < 16; ++r) { acc0[r] *= 0.03125f; acc1[r] *= 0.03125f; }

    // epilogue: sep[b 64][cjp_local 128], XOR-swizzled by b
    #pragma unroll
    for (int hb = 0; hb < 2; ++hb) {
        #pragma unroll
        for (int q = 0; q < 8; ++q) {
            const float e0 = hb ? acc1[2 * q] : acc0[2 * q];
            const float e1 = hb ? acc1[2 * q + 1] : acc0[2 * q + 1];
            U2 u; u.h = __builtin_amdgcn_cvt_pkrtz(e0, e1);
            const int cjp = w * 16 + 4 * (q >> 1) + (q & 1) + 2 * hi;  // local
            const int bb = bl + 32 * hb;
            sep[bb * 128 + (cjp ^ bb)] = u.u;
        }
    }
    __syncthreads();
    #pragma unroll
    for (int u2 = 0; u2 < 16; ++u2) {
        const int idx = t + u2 * 512;                // 0..8191
        const int ub = idx >> 7, ucjp = idx & 127;
        partial[(size_t)((ub >> 5) * NB + nblk) * 8192 + (ub & 31) * 256 + half * 128 + ucjp]
            = sep[ub * 128 + (ucjp ^ ub)];
    }
}

// ---- pass 1/2: softmax coupling; Wh via async LDS staging; fp16 acc -------

template <int NPB>
__global__ __launch_bounds__(512, 4) void pass12_kernel(
    const ushort* __restrict__ Wh,    // [np][cj][hi][par][i4] fp16
    const ushort* __restrict__ xh,    // [np][b][hi][par][i4] fp16
    const ushort* __restrict__ OcumG, // [B][CJ] fp16
    unsigned* __restrict__ partial)   // [bid][bl 32][cjp 256] u32(h2)
{
    constexpr int NB = 4096 / NPB;
    const int bid = blockIdx.x;
    const int bt = bid / NB, nblk = bid % NB;
    const int n0 = nblk * NPB;
    const int t = threadIdx.x, l = t & 63, w = t >> 6;
    const int bl = l & 31, hi = l >> 5;
    const int b = bt * 32 + bl;

    // whs: double-buffered Wh n-pair slice, chunk v = cj + 512*hi (16B each).
    // sep (epilogue-only) unions onto whs. pd separate.
    __shared__ __align__(16) ushort whs[2][8192];    // 2 x 16 KB
    __shared__ __align__(16) float pd[2][2][32][12]; // [buf][sub][b][wave]
    unsigned* sep = reinterpret_cast<unsigned*>(&whs[0][0]);

    const int cj0 = w * 64 + bl, cj1 = cj0 + 32;
    const ushort* xb = xh + (((size_t)(n0 >> 1) * 64 + b) * 2 + hi) * 8;

    // wave-level async stage of np-slice (n0/2 + pslice) into whs[nbuf]
    const int wvl = w;                                // wave id 0..7
    auto stage = [&](int pslice, int nbuf) {
        const ushort* g0 = Wh + ((size_t)((n0 >> 1) + pslice) * 512 + wvl * 64 + l) * 16;
        lds_us* lb0 = (lds_us*)(void*)&whs[nbuf][(wvl * 64) * 8];          // hi=0 chunks
        lds_us* lb1 = (lds_us*)(void*)&whs[nbuf][(512 + wvl * 64) * 8];    // hi=1 chunks
        __builtin_amdgcn_global_load_lds((glb_us*)g0, lb0, 16, 0, 0);
        __builtin_amdgcn_global_load_lds((glb_us*)(g0 + 8), lb1, 16, 0, 0);
    };

    h2 oc[2][8];
    {
        const unsigned* og = reinterpret_cast<const unsigned*>(OcumG);
        #pragma unroll
        for (int mt = 0; mt < 2; ++mt) {
            const int cA = 4 * w + 2 * mt;
            const unsigned idx = (unsigned)b * 256 + cA * 8 + hi * 2;
            oc[mt][0] = uash2(og[idx]);      oc[mt][1] = uash2(og[idx + 1]);
            oc[mt][2] = uash2(og[idx + 4]);  oc[mt][3] = uash2(og[idx + 5]);
            oc[mt][4] = uash2(og[idx + 8]);  oc[mt][5] = uash2(og[idx + 9]);
            oc[mt][6] = uash2(og[idx + 12]); oc[mt][7] = uash2(og[idx + 13]);
        }
    }

    f32x16 zero = {};
    h2 acc0h[8], acc1h[8];                           // fp16 accumulators
    #pragma unroll
    for (int q = 0; q < 8; ++q) {
        acc0h[q] = (h2)(__fp16)0.f;
        acc1h[q] = (h2)(__fp16)0.f;
    }

    stage(0, 0);
    __syncthreads();                                 // vmcnt drain: buf0 ready

    uint4 xv = *reinterpret_cast<const uint4*>(xb);

    #pragma unroll 1
    for (int p = 0; p < NPB / 2; ++p) {
        const int cur = p & 1;
        if (p + 1 < NPB / 2)
            stage(p + 1, cur ^ 1);                   // async; lands by next barrier
        uint4 xvn;
        if (p < NPB / 2 - 1)
            xvn = *reinterpret_cast<const uint4*>(xb + (size_t)(p + 1) * 1024);

        const ushort* wcur = &whs[cur][0];
        const uint4 w0 = *reinterpret_cast<const uint4*>(wcur + (cj0 + (hi << 9)) * 8);
        const uint4 w1 = *reinterpret_cast<const uint4*>(wcur + (cj1 + (hi << 9)) * 8);
        const half4* w0h = reinterpret_cast<const half4*>(&w0);
        const half4* w1h = reinterpret_cast<const half4*>(&w1);
        const half4* xvh = reinterpret_cast<const half4*>(&xv);
        const half4 a0A = w0h[0], a0B = w0h[1];
        const half4 a1A = w1h[0], a1B = w1h[1];
        const half4 bfA = xvh[0], bfB = xvh[1];

        // ---- sub-step A -----------------------------------------------
        h2 hA0[8], hA1[8];
        {
            f32x16 d0 = __builtin_amdgcn_mfma_f32_32x32x8f16(a0A, bfA, zero, 0, 0, 0);
            f32x16 d1 = __builtin_amdgcn_mfma_f32_32x32x8f16(a1A, bfA, zero, 0, 0, 0);
            #pragma unroll
            for (int q = 0; q < 8; ++q) {
                hA0[q] = __builtin_amdgcn_cvt_pkrtz(d0[2 * q], d0[2 * q + 1]);
                hA1[q] = __builtin_amdgcn_cvt_pkrtz(d1[2 * q], d1[2 * q + 1]);
            }
        }
        float pA0_A = fdot2(hA0[3], oc[0][3], fdot2(hA0[2], oc[0][2], fdot2(hA0[1], oc[0][1], fdot2(hA0[0], oc[0][0], 0.f))));
        float pB0_A = fdot2(hA0[7], oc[0][7], fdot2(hA0[6], oc[0][6], fdot2(hA0[5], oc[0][5], fdot2(hA0[4], oc[0][4], 0.f))));
        float pA1_A = fdot2(hA1[3], oc[1][3], fdot2(hA1[2], oc[1][2], fdot2(hA1[1], oc[1][1], fdot2(hA1[0], oc[1][0], 0.f))));
        float pB1_A = fdot2(hA1[7], oc[1][7], fdot2(hA1[6], oc[1][6], fdot2(hA1[5], oc[1][5], fdot2(hA1[4], oc[1][4], 0.f))));
        // ---- sub-step B -----------------------------------------------
        h2 hB0[8], hB1[8];
        {
            f32x16 d0 = __builtin_amdgcn_mfma_f32_32x32x8f16(a0B, bfB, zero, 0, 0, 0);
            f32x16 d1 = __builtin_amdgcn_mfma_f32_32x32x8f16(a1B, bfB, zero, 0, 0, 0);
            #pragma unroll
            for (int q = 0; q < 8; ++q) {
                hB0[q] = __builtin_amdgcn_cvt_pkrtz(d0[2 * q], d0[2 * q + 1]);
                hB1[q] = __builtin_amdgcn_cvt_pkrtz(d1[2 * q], d1[2 * q + 1]);
            }
        }
        float pA0_B = fdot2(hB0[3], oc[0][3], fdot2(hB0[2], oc[0][2], fdot2(hB0[1], oc[0][1], fdot2(hB0[0], oc[0][0], 0.f))));
        float pB0_B = fdot2(hB0[7], oc[0][7], fdot2(hB0[6], oc[0][6], fdot2(hB0[5], oc[0][5], fdot2(hB0[4], oc[0][4], 0.f))));
        float pA1_B = fdot2(hB1[3], oc[1][3], fdot2(hB1[2], oc[1][2], fdot2(hB1[1], oc[1][1], fdot2(hB1[0], oc[1][0], 0.f))));
        float pB1_B = fdot2(hB1[7], oc[1][7], fdot2(hB1[6], oc[1][6], fdot2(hB1[5], oc[1][5], fdot2(hB1[4], oc[1][4], 0.f))));

        pA0_A += __shfl_xor(pA0_A, 32, 64);
        pB0_A += __shfl_xor(pB0_A, 32, 64);
        pA1_A += __shfl_xor(pA1_A, 32, 64);
        pB1_A += __shfl_xor(pB1_A, 32, 64);
        pA0_B += __shfl_xor(pA0_B, 32, 64);
        pB0_B += __shfl_xor(pB0_B, 32, 64);
        pA1_B += __shfl_xor(pA1_B, 32, 64);
        pB1_B += __shfl_xor(pB1_B, 32, 64);

        float eA0_A = __expf(pA0_A), eB0_A = __expf(pB0_A);
        float eA1_A = __expf(pA1_A), eB1_A = __expf(pB1_A);
        float eA0_B = __expf(pA0_B), eB0_B = __expf(pB0_B);
        float eA1_B = __expf(pA1_B), eB1_B = __expf(pB1_B);

        const int buf = p & 1;
        if (l < 32) {
            pd[buf][0][bl][w] = eA0_A + eB0_A + eA1_A + eB1_A;
            pd[buf][1][bl][w] = eA0_B + eB0_B + eA1_B + eB1_B;
        }
        __syncthreads();   // pd ready AND staged slice (p+1) landed (vmcnt drain)
        const float4 qa0 = *reinterpret_cast<const float4*>(&pd[buf][0][bl][0]);
        const float4 qa1 = *reinterpret_cast<const float4*>(&pd[buf][0][bl][4]);
        const float4 qb0 = *reinterpret_cast<const float4*>(&pd[buf][1][bl][0]);
        const float4 qb1 = *reinterpret_cast<const float4*>(&pd[buf][1][bl][4]);
        const float rdA = __builtin_amdgcn_rcpf(qa0.x + qa0.y + qa0.z + qa0.w +
                                                qa1.x + qa1.y + qa1.z + qa1.w);
        const float rdB = __builtin_amdgcn_rcpf(qb0.x + qb0.y + qb0.z + qb0.w +
                                                qb1.x + qb1.y + qb1.z + qb1.w);

        h2 c0A, c1A, c0B, c1B, c2A, c3A, c2B, c3B;
        c0A.x = (__fp16)(eA0_A * rdA); c0A.y = c0A.x;  // acc0 rows<8  (c=4w)
        c1A.x = (__fp16)(eB0_A * rdA); c1A.y = c1A.x;  // acc0 rows>=8 (c=4w+1)
        c2A.x = (__fp16)(eA1_A * rdA); c2A.y = c2A.x;  // acc1 rows<8  (c=4w+2)
        c3A.x = (__fp16)(eB1_A * rdA); c3A.y = c3A.x;  // acc1 rows>=8 (c=4w+3)
        c0B.x = (__fp16)(eA0_B * rdB); c0B.y = c0B.x;
        c1B.x = (__fp16)(eB0_B * rdB); c1B.y = c1B.x;
        c2B.x = (__fp16)(eA1_B * rdB); c2B.y = c2B.x;
        c3B.x = (__fp16)(eB1_B * rdB); c3B.y = c3B.x;

        #pragma unroll
        for (int q = 0; q < 4; ++q) {
            acc0h[q] = hA0[q] * c0A + acc0h[q];
            acc0h[q + 4] = hA0[q + 4] * c1A + acc0h[q + 4];
            acc1h[q] = hA1[q] * c2A + acc1h[q];
            acc1h[q + 4] = hA1[q + 4] * c3A + acc1h[q + 4];
        }
        #pragma unroll
        for (int q = 0; q < 4; ++q) {
            acc0h[q] = hB0[q] * c0B + acc0h[q];
            acc0h[q + 4] = hB0[q + 4] * c1B + acc0h[q + 4];
            acc1h[q] = hB1[q] * c2B + acc1h[q];
            acc1h[q + 4] = hB1[q + 4] * c3B + acc1h[q + 4];
        }
        xv = xvn;
    }

    // ---- epilogue: stage h2 partial tile in LDS (XOR-swizzled), copy out --
    __syncthreads();                                 // whs dead -> sep reuses it
    #pragma unroll
    for (int mt = 0; mt < 2; ++mt) {
        #pragma unroll
        for (int q = 0; q < 8; ++q) {
            U2 u; u.h = mt ? acc1h[q] : acc0h[q];
            const int cjp = w * 32 + mt * 16 + 4 * (q >> 1) + (q & 1) + 2 * hi;
            sep[bl * 256 + (cjp ^ bl)] = u.u;   // swizzle: conflict-free banks
        }
    }
    __syncthreads();
    const unsigned gbase = (unsigned)bid * 8192;
    #pragma unroll
    for (int u2 = 0; u2 < 16; ++u2) {
        const int idx = t + u2 * 512;
        const int ubl = idx >> 8, ucjp = idx & 255;
        partial[gbase + idx] = sep[ubl * 256 + (ucjp ^ ubl)];
    }
}

// ---- final reduce + squash + Ocum update (4 threads per output) -----------

template <int NB>
__global__ __launch_bounds__(256) void reduce_squash(const unsigned* __restrict__ partial32,
                                                     ushort* __restrict__ OcumG,
                                                     float* __restrict__ out,
                                                     int passIdx) {
    const int gtid = blockIdx.x * 256 + threadIdx.x;  // 0..65535
    const int oid = gtid >> 2, sub = gtid & 3;
    const int b = oid >> 8, cjp = oid & 255;
    const int bt = b >> 5, bl = b & 31;
    const unsigned base = (unsigned)bt * (unsigned)NB * 8192u + (unsigned)bl * 256u + (unsigned)cjp;
    float sx = 0.f, sy = 0.f;
    #pragma unroll 8
    for (int i = 0; i < NB / 4; ++i) {
        U2 v; v.u = partial32[base + (unsigned)(sub + 4 * i) * 8192u];
        sx += (float)v.h.x;
        sy += (float)v.h.y;
    }
    sx += __shfl_xor(sx, 1, 64); sy += __shfl_xor(sy, 1, 64);
    sx += __shfl_xor(sx, 2, 64); sy += __shfl_xor(sy, 2, 64);
    float s2 = sx * sx + sy * sy;                    // sum over capsule's 8 cjp
    s2 += __shfl_xor(s2, 4, 64);
    s2 += __shfl_xor(s2, 8, 64);
    s2 += __shfl_xor(s2, 16, 64);
    float scale = (s2 / (1.f + s2)) / sqrtf(s2 + 1e-7f);
    float o0 = scale * sx, o1 = scale * sy;

    if (sub == 0) {
        unsigned* ocp = reinterpret_cast<unsigned*>(OcumG) + b * 256 + cjp;
        float a0 = o0, a1 = o1;
        if (passIdx) {
            U2 old; old.u = *ocp;
            a0 += (float)old.h.x;
            a1 += (float)old.h.y;
        }
        U2 nw; nw.h = __builtin_amdgcn_cvt_pkrtz(a0, a1);
        *ocp = nw.u;
        if (passIdx == 2) {
            out[b * 512 + cjp * 2] = o0;
            out[b * 512 + cjp * 2 + 1] = o1;
        }
    }
}

// ---- host ------------------------------------------------------------------

extern "C" void kernel_launch(void* const* d_in, const int* in_sizes, int n_in,
                              void* d_out, int out_size, void* d_ws, size_t ws_size,
                              hipStream_t stream) {
    const float* x = (const float*)d_in[0];
    const float* W = (const float*)d_in[1];
    float* out = (float*)d_out;

    char* ws = (char*)d_ws;
    ushort* Wh = (ushort*)ws;                                        // 32 MiB
    const size_t MiB = 1024 * 1024;

    if (ws_size >= 52 * MiB + 65536) {
        // NPB=16: partial 16 MiB | xh 4 MiB | Ocum 64 KiB
        unsigned* partialU = (unsigned*)(ws + 32 * MiB);
        ushort* xh = (ushort*)(ws + 48 * MiB);
        ushort* OcumG = (ushort*)(ws + 52 * MiB);
        pass0_kernel<16><<<512, 512, 0, stream>>>(W, x, Wh, xh, partialU);
        reduce_squash<256><<<256, 256, 0, stream>>>(partialU, OcumG, out, 0);
        pass12_kernel<16><<<512, 512, 0, stream>>>(Wh, xh, OcumG, partialU);
        reduce_squash<256><<<256, 256, 0, stream>>>(partialU, OcumG, out, 1);
        pass12_kernel<16><<<512, 512, 0, stream>>>(Wh, xh, OcumG, partialU);
        reduce_squash<256><<<256, 256, 0, stream>>>(partialU, OcumG, out, 2);
    } else {
        // fallback NPB=32: partial 8 MiB | xh 4 MiB | Ocum 64 KiB (44.07 MiB)
        unsigned* partialU = (unsigned*)(ws + 32 * MiB);
        ushort* xh = (ushort*)(ws + 40 * MiB);
        ushort* OcumG = (ushort*)(ws + 44 * MiB);
        pass0_kernel<32><<<256, 512, 0, stream>>>(W, x, Wh, xh, partialU);
        reduce_squash<128><<<256, 256, 0, stream>>>(partialU, OcumG, out, 0);
        pass12_kernel<32><<<256, 512, 0, stream>>>(Wh, xh, OcumG, partialU);
        reduce_squash<128><<<256, 256, 0, stream>>>(partialU, OcumG, out, 1);
        pass12_kernel<32><<<256, 512, 0, stream>>>(Wh, xh, OcumG, partialU);
        reduce_squash<128><<<256, 256, 0, stream>>>(partialU, OcumG, out, 2);
    }
}